// Round 1
// baseline (2254.747 us; speedup 1.0000x reference)
//
#include <hip/hip_runtime.h>
#include <hip/hip_bf16.h>

#define NEG_SLOPE 0.2f
#define STATS_SPLIT 50

// ---------------------------------------------------------------------------
// K1: h = input @ W_fc  (N x 128) @ (128 x 128), fused el/er head reductions.
// W_fc staged in LDS (64 KB); 8 rows per iteration, broadcast LDS reads.
// ---------------------------------------------------------------------------
__global__ __launch_bounds__(128) void fc_kernel(
    const float* __restrict__ in, const float* __restrict__ W,
    const float* __restrict__ attn_l, const float* __restrict__ attn_r,
    float* __restrict__ h, float* __restrict__ el, float* __restrict__ er,
    int n)
{
    extern __shared__ float smem[];
    float* Wl = smem;                 // 128*128
    float* rowbuf = smem + 128 * 128; // 8*128
    const int tid = threadIdx.x;

    for (int i = tid; i < 128 * 128; i += 128) Wl[i] = W[i];
    const float al = attn_l[tid];
    const float ar = attn_r[tid];
    __syncthreads();

    for (int base = blockIdx.x * 8; base < n; base += gridDim.x * 8) {
        const int nr = min(8, n - base);
        for (int i = tid; i < nr * 128; i += 128)
            rowbuf[i] = in[(long long)(base + (i >> 7)) * 128 + (i & 127)];
        __syncthreads();

        float acc[8] = {0.f, 0.f, 0.f, 0.f, 0.f, 0.f, 0.f, 0.f};
        for (int k = 0; k < 128; ++k) {
            const float w = Wl[k * 128 + tid];
#pragma unroll
            for (int r = 0; r < 8; ++r)
                acc[r] += rowbuf[r * 128 + k] * w;
        }

#pragma unroll
        for (int r = 0; r < 8; ++r) {
            if (r >= nr) break;
            const long long row = base + r;
            h[row * 128 + tid] = acc[r];
            float vl = acc[r] * al;
            float vr = acc[r] * ar;
#pragma unroll
            for (int off = 8; off >= 1; off >>= 1) {
                vl += __shfl_xor(vl, off, 64);
                vr += __shfl_xor(vr, off, 64);
            }
            if ((tid & 15) == 0) {
                const int hd = tid >> 4;
                el[row * 8 + hd] = vl;
                er[row * 8 + hd] = vr;
            }
        }
        __syncthreads();
    }
}

// ---------------------------------------------------------------------------
// K2: per-edge exp(leaky_relu(el[src]+er[dst])) accumulated into denom[dst].
// (Max-subtraction skipped: softmax is invariant; |e| is O(1) here.)
// ---------------------------------------------------------------------------
__global__ __launch_bounds__(256) void edge_denom_kernel(
    const float* __restrict__ el, const float* __restrict__ er,
    const int* __restrict__ src, const int* __restrict__ dst,
    float* __restrict__ denom, int E)
{
    const int i = blockIdx.x * 256 + threadIdx.x;
    if (i >= E) return;
    const int s = src[i], d = dst[i];
    const float4* lp = (const float4*)(el + (long long)s * 8);
    const float4* rp = (const float4*)(er + (long long)d * 8);
    const float4 l0 = lp[0], l1 = lp[1];
    const float4 r0 = rp[0], r1 = rp[1];
    float e[8] = {l0.x + r0.x, l0.y + r0.y, l0.z + r0.z, l0.w + r0.w,
                  l1.x + r1.x, l1.y + r1.y, l1.z + r1.z, l1.w + r1.w};
#pragma unroll
    for (int j = 0; j < 8; ++j) {
        float v = e[j];
        v = v >= 0.f ? v : NEG_SLOPE * v;
        atomicAdd(&denom[(long long)d * 8 + j], expf(v));
    }
}

// ---------------------------------------------------------------------------
// K3: message pass. One thread per (edge, feature): rst[dst][f] += a*h[src][f]
// ---------------------------------------------------------------------------
__global__ __launch_bounds__(256) void edge_msg_kernel(
    const float* __restrict__ el, const float* __restrict__ er,
    const float* __restrict__ denom, const float* __restrict__ h,
    const int* __restrict__ src, const int* __restrict__ dst,
    float* __restrict__ rst, int E)
{
    const long long gid = (long long)blockIdx.x * 256 + threadIdx.x;
    const int edge = (int)(gid >> 7);
    if (edge >= E) return;
    const int f = (int)(gid & 127);
    const int s = src[edge], d = dst[edge];
    const int hd = f >> 4;
    float e = el[(long long)s * 8 + hd] + er[(long long)d * 8 + hd];
    e = e >= 0.f ? e : NEG_SLOPE * e;
    const float a = expf(e) / denom[(long long)d * 8 + hd];
    atomicAdd(&rst[(long long)d * 128 + f], a * h[(long long)s * 128 + f]);
}

// ---------------------------------------------------------------------------
// K4: GCNII combine. x = theta*(concat(rst+bias, h0) @ W_comb)
//                      + (1-theta)*((1-alpha)*(rst+bias) + alpha*h0) + input
// W_comb (256x128 = 128 KB) in dynamic LDS. Writes straight into d_out.
// ---------------------------------------------------------------------------
__global__ __launch_bounds__(128) void combine_kernel(
    const float* __restrict__ rst, const float* __restrict__ gat_bias,
    const float* __restrict__ h0, const float* __restrict__ input,
    const float* __restrict__ W, const int* __restrict__ l_p,
    const float* __restrict__ lamda_p, const float* __restrict__ alpha_p,
    float* __restrict__ x, int n)
{
    extern __shared__ float smem[];
    float* Wl = smem;                // 256*128
    float* sup = smem + 256 * 128;   // 8*256
    const int tid = threadIdx.x;

    for (int i = tid; i < 256 * 128; i += 128) Wl[i] = W[i];
    const float bias = gat_bias[tid];
    const float alpha = alpha_p[0];
    const float theta = fminf(1.0f, logf(lamda_p[0] / (float)l_p[0] + 1.0f));
    __syncthreads();

    for (int base = blockIdx.x * 8; base < n; base += gridDim.x * 8) {
        const int nr = min(8, n - base);
        for (int r = 0; r < nr; ++r) {
            const long long row = base + r;
            sup[r * 256 + tid] = rst[row * 128 + tid] + bias;
            sup[r * 256 + 128 + tid] = h0[row * 128 + tid];
        }
        __syncthreads();

        float acc[8] = {0.f, 0.f, 0.f, 0.f, 0.f, 0.f, 0.f, 0.f};
        for (int k = 0; k < 256; ++k) {
            const float w = Wl[k * 128 + tid];
#pragma unroll
            for (int r = 0; r < 8; ++r)
                acc[r] += sup[r * 256 + k] * w;
        }

#pragma unroll
        for (int r = 0; r < 8; ++r) {
            if (r >= nr) break;
            const long long row = base + r;
            const float xg = sup[r * 256 + tid];
            const float h0v = sup[r * 256 + 128 + tid];
            const float rr = (1.f - alpha) * xg + alpha * h0v;
            x[row * 128 + tid] =
                theta * acc[r] + (1.f - theta) * rr + input[row * 128 + tid];
        }
        __syncthreads();
    }
}

// ---------------------------------------------------------------------------
// K5: per-subgraph partial sums (split-K over nodes, atomics into (B,128)).
// ---------------------------------------------------------------------------
__global__ __launch_bounds__(128) void stats_kernel(
    const float* __restrict__ x, const int* __restrict__ cums,
    float* __restrict__ sums, float* __restrict__ sumsq)
{
    const int b = blockIdx.x / STATS_SPLIT;
    const int part = blockIdx.x % STATS_SPLIT;
    const int tid = threadIdx.x;
    const int start = cums[b], end = cums[b + 1];
    float s = 0.f, s2 = 0.f;
    for (int node = start + part; node < end; node += STATS_SPLIT) {
        const float v = x[(long long)node * 128 + tid];
        s += v;
        s2 += v * v;
    }
    atomicAdd(&sums[b * 128 + tid], s);
    atomicAdd(&sumsq[b * 128 + tid], s2);
}

// K6: sums -> mean, sumsq -> 1/(std+eps)  (unbiased, n-1)
__global__ __launch_bounds__(128) void finalize_stats_kernel(
    const int* __restrict__ cums, float* __restrict__ sums,
    float* __restrict__ sumsq)
{
    const int b = blockIdx.x;
    const int tid = threadIdx.x;
    const float cnt = (float)(cums[b + 1] - cums[b]);
    const float s = sums[b * 128 + tid];
    const float s2 = sumsq[b * 128 + tid];
    const float mean = s / cnt;
    float var = (s2 - s * mean) / (cnt - 1.f);
    var = fmaxf(var, 0.f);
    sums[b * 128 + tid] = mean;
    sumsq[b * 128 + tid] = 1.f / (sqrtf(var) + 1e-5f);
}

// K7: out = gamma * (x - mean[sid]) * istd[sid] + beta   (in-place on d_out)
__global__ __launch_bounds__(256) void norm_kernel(
    const float* __restrict__ x, const float* __restrict__ mean,
    const float* __restrict__ istd, const int* __restrict__ cums, int nb,
    const float* __restrict__ gamma, const float* __restrict__ beta,
    float* __restrict__ out, int n)
{
    const long long gid = (long long)blockIdx.x * 256 + threadIdx.x;
    const int node = (int)(gid >> 7);
    if (node >= n) return;
    const int f = (int)(gid & 127);
    int lo = 0, hi = nb;
    while (hi - lo > 1) {
        const int mid = (lo + hi) >> 1;
        if (cums[mid] <= node) lo = mid; else hi = mid;
    }
    const float m = mean[lo * 128 + f];
    const float is = istd[lo * 128 + f];
    const float v = x[gid];
    out[gid] = gamma[f] * ((v - m) * is) + beta[f];
}

// ---------------------------------------------------------------------------
extern "C" void kernel_launch(void* const* d_in, const int* in_sizes, int n_in,
                              void* d_out, int out_size, void* d_ws, size_t ws_size,
                              hipStream_t stream) {
    const float* input   = (const float*)d_in[0];
    const float* h0      = (const float*)d_in[1];
    const int*   src     = (const int*)d_in[2];
    const int*   dst     = (const int*)d_in[3];
    const int*   cums    = (const int*)d_in[4];
    const int*   l_p     = (const int*)d_in[5];
    const float* lamda_p = (const float*)d_in[6];
    const float* alpha_p = (const float*)d_in[7];
    const float* W_fc    = (const float*)d_in[8];
    const float* attn_l  = (const float*)d_in[9];
    const float* attn_r  = (const float*)d_in[10];
    const float* gat_bias= (const float*)d_in[11];
    const float* W_comb  = (const float*)d_in[12];
    const float* gamma   = (const float*)d_in[13];
    const float* beta    = (const float*)d_in[14];

    const int n  = in_sizes[0] / 128;
    const int E  = in_sizes[2];
    const int nb = in_sizes[4] - 1;
    float* out = (float*)d_out;

    // workspace layout
    char* ws = (char*)d_ws;
    size_t o = 0;
    float* h     = (float*)(ws + o); o += (size_t)n * 128 * 4;
    float* el    = (float*)(ws + o); o += (size_t)n * 8 * 4;
    float* er    = (float*)(ws + o); o += (size_t)n * 8 * 4;
    float* denom = (float*)(ws + o); o += (size_t)n * 8 * 4;
    float* rst   = (float*)(ws + o); o += (size_t)n * 128 * 4;
    float* sums  = (float*)(ws + o); o += (size_t)nb * 128 * 4;
    float* sumsq = (float*)(ws + o); o += (size_t)nb * 128 * 4;

    hipMemsetAsync(denom, 0, (size_t)n * 8 * 4, stream);
    hipMemsetAsync(rst, 0, (size_t)n * 128 * 4, stream);
    hipMemsetAsync(sums, 0, (size_t)nb * 128 * 4 * 2, stream); // sums+sumsq contiguous

    fc_kernel<<<1024, 128, (128 * 128 + 8 * 128) * 4, stream>>>(
        input, W_fc, attn_l, attn_r, h, el, er, n);

    edge_denom_kernel<<<(E + 255) / 256, 256, 0, stream>>>(
        el, er, src, dst, denom, E);

    const long long msg_threads = (long long)E * 128;
    edge_msg_kernel<<<(int)((msg_threads + 255) / 256), 256, 0, stream>>>(
        el, er, denom, h, src, dst, rst, E);

    combine_kernel<<<2048, 128, (256 * 128 + 8 * 256) * 4, stream>>>(
        rst, gat_bias, h0, input, W_comb, l_p, lamda_p, alpha_p, out, n);

    stats_kernel<<<nb * STATS_SPLIT, 128, 0, stream>>>(out, cums, sums, sumsq);
    finalize_stats_kernel<<<nb, 128, 0, stream>>>(cums, sums, sumsq);

    const long long norm_threads = (long long)n * 128;
    norm_kernel<<<(int)((norm_threads + 255) / 256), 256, 0, stream>>>(
        out, sums, sumsq, cums, nb, gamma, beta, out, n);
}